// Round 14
// baseline (140.355 us; speedup 1.0000x reference)
//
#include <hip/hip_runtime.h>
#include <hip/hip_bf16.h>

typedef __attribute__((ext_vector_type(8))) short sh8;        // 8 x bf16 bits (4 VGPR)
typedef __attribute__((ext_vector_type(16))) float fx16;      // MFMA 32x32 accumulator
typedef __attribute__((ext_vector_type(4))) unsigned int u32x4;

__device__ __forceinline__ unsigned short f2bits(float a) {
  union { __hip_bfloat16 h; unsigned short u; } c;
  c.h = __float2bfloat16(a);
  return c.u;
}
// one-instruction RNE pack: lo = cvt(a), hi = cvt(b)
__device__ __forceinline__ unsigned int pkcvt(float a, float b) {
  unsigned int r;
  asm("v_cvt_pk_bf16_f32 %0, %1, %2" : "=v"(r) : "v"(a), "v"(b));
  return r;
}
__device__ __forceinline__ fx16 fzero16() {
  fx16 z;
  #pragma unroll
  for (int i = 0; i < 16; ++i) z[i] = 0.0f;
  return z;
}

// ---------------------------------------------------------------------------
// Kernel 1: batched Cayley transform Q = (I-A)(I+A)^-1 for P1 (64) and P2 (64).
// ---------------------------------------------------------------------------
__global__ void k_cayley(const float* __restrict__ P1, const float* __restrict__ P2,
                         float* __restrict__ Qout) {
  int t = blockIdx.x * blockDim.x + threadIdx.x;
  int mat = t >> 4;
  int row = t & 15;
  if (mat >= 128) return;
  const float* P = (mat < 64) ? (P1 + mat * 256) : (P2 + (mat - 64) * 256);
  float M[16], Rr[16];
  #pragma unroll
  for (int j = 0; j < 16; ++j) {
    float a = 0.0f;
    if (j > row) a = P[row * 16 + j];
    if (j < row) a = -P[j * 16 + row];
    float d = (j == row) ? 1.0f : 0.0f;
    M[j]  = d + a;
    Rr[j] = d - a;
  }
  int gbase = (threadIdx.x & 63) & ~15;
  #pragma unroll
  for (int k = 0; k < 16; ++k) {
    float pkk = __shfl(M[k], gbase + k);
    float inv = 1.0f / pkk;
    float pM[16], pR[16];
    #pragma unroll
    for (int j = 0; j < 16; ++j) {
      pM[j] = __shfl(M[j], gbase + k) * inv;
      pR[j] = __shfl(Rr[j], gbase + k) * inv;
    }
    if (row == k) {
      #pragma unroll
      for (int j = 0; j < 16; ++j) { M[j] = pM[j]; Rr[j] = pR[j]; }
    } else {
      float f = M[k];
      #pragma unroll
      for (int j = 0; j < 16; ++j) { M[j] -= f * pM[j]; Rr[j] -= f * pR[j]; }
    }
  }
  float* qo = Qout + mat * 256 + row * 16;
  #pragma unroll
  for (int j = 0; j < 16; ++j) qo[j] = Rr[j];
}

// ---------------------------------------------------------------------------
// Kernel 2: build folded weights in bf16, MFMA B-fragment order.
// W1[t2][tile(2)][kstep(4)][lane(64)][r(8)]: k-map q = kstep*16 + 8h + r.
// W2[t2][tile(2)][kstep(4)][lane(64)][r(8)]: k-map s = kstep*16 + sigma(h,r),
//   sigma(h,r) = (r&3) + 8*(r>>2) + 4h  -- so GEMM2's A-frag is accY regs
//   in order after v_cvt_pk (no cross-lane permute).
// ---------------------------------------------------------------------------
__global__ void k_build(const float* __restrict__ P0, const float* __restrict__ P3,
                        const float* __restrict__ Qbuf,
                        unsigned short* __restrict__ W1, unsigned short* __restrict__ W2) {
  int t = blockIdx.x * blockDim.x + threadIdx.x;
  if (t >= 131072) return;
  const float* Q1 = Qbuf;
  const float* Q2 = Qbuf + 16384;
  int e  = t & 65535;
  int r  = e & 7;
  int l  = (e >> 3) & 63;
  int kx = (e >> 9) & 3;
  int mt = (e >> 11) & 1;
  int t2 = (e >> 12) & 15;
  float acc = 0.0f;
  if (t < 65536) {
    int m = mt * 32 + (l & 31);
    int q = kx * 16 + ((l >> 5) << 3) + r;
    int j0 = m >> 3, j1 = m & 7, i0 = q >> 3, i1 = q & 7;
    #pragma unroll
    for (int t1 = 0; t1 < 16; ++t1) {
      float c0 = P0[(j0 * 8 + (t1 >> 1)) * 16 + ((t1 & 1) * 8 + i0)];
      int a1 = j1 * 16 + t2, u1 = t1 * 8 + i1;
      float c1 = Q1[((a1 & 7) * 8 + (u1 >> 4)) * 256 + (a1 >> 3) * 16 + (u1 & 15)];
      acc += c0 * c1;
    }
    W1[e] = f2bits(acc);
  } else {
    int n = mt * 32 + (l & 31);
    int s = kx * 16 + (r & 3) + 8 * (r >> 2) + 4 * (l >> 5);   // sigma-permuted k-map
    int j2 = n >> 3, j3 = n & 7, i2 = s >> 3, i3 = s & 7;
    #pragma unroll
    for (int t3 = 0; t3 < 16; ++t3) {
      int a2 = j2 * 16 + t3, u2 = t2 * 8 + i2;
      float c2 = Q2[((a2 & 7) * 8 + (u2 >> 4)) * 256 + (a2 >> 3) * 16 + (u2 & 15)];
      float c3 = P3[((t3 & 7) * 8 + i3) * 16 + (j3 * 2 + (t3 >> 3))];
      acc += c2 * c3;
    }
    W2[e] = f2bits(acc);
  }
}

// ---------------------------------------------------------------------------
// Kernel 3 (R13 + T4 counted-vmcnt sync: never drain to 0 in the loop).
// WG = 4 waves / 4 batch elems; wave = (elem-pair, m-half). W2 slices in a
// TRIPLE-buffered LDS ring, staged 2 iterations ahead; b1 via VMEM regs
// reloaded one iter ahead. Per-iter sync = s_waitcnt vmcnt(16) [= exactly
// b1(t2-1)4 + stage(t2+1)8 + b1(t2)4 allowed in flight; in-order retirement
// => stage(t2) landed] + raw s_barrier (placed BEFORE the stage-issue to
// fence the ring-buffer WAR). Stage cover ~2 iterations. 2 WGs/CU.
// ---------------------------------------------------------------------------
__global__ __launch_bounds__(256, 2) void k_main(
    const float* __restrict__ x,
    const unsigned short* __restrict__ W1,
    const unsigned short* __restrict__ W2,
    const float* __restrict__ bias,
    float* __restrict__ out) {
  __shared__ __align__(16) char smem[4 * 8192 + 3 * 8192];
  char* XsT = smem;                 // [elem][64 s][128 B], swizzled
  char* WL  = smem + 32768;         // [3][8192]: ring of W2 slices

  const int tid  = threadIdx.x;
  const int lane = tid & 63;
  const int w    = tid >> 6;
  const int h    = lane >> 5;
  const int l31  = lane & 31;
  const int ep   = (w >> 1) * 2;    // first elem of this wave's pair
  const int mh   = w & 1;           // m-half this wave owns
  const size_t bbase = (size_t)blockIdx.x * 4;

  const char* w2c = (const char*)W2;
  const sh8* w1f = (const sh8*)W1;   // idx: t2*512 + (tile*4+kstep)*64 + lane

  // ---- prologue: stage W2(0) and W2(1) into ring slots 0,1 ----
  #pragma unroll
  for (int t = 0; t < 2; ++t) {
    char* dst = WL + t * 8192;
    #pragma unroll
    for (int c = 0; c < 2; ++c) {
      const char* src = w2c + (size_t)t * 8192 + c * 4096 + w * 1024 + lane * 16;
      __builtin_amdgcn_global_load_lds((const unsigned int*)src,
                                       (unsigned int*)(dst + c * 4096 + w * 1024),
                                       16, 0, 0);
    }
  }

  // ---- b1(0) into regs (VMEM; latency covered by X staging) ----
  sh8 b1[4];
  #pragma unroll
  for (int kq = 0; kq < 4; ++kq)
    b1[kq] = w1f[(mh * 4 + kq) * 64 + lane];

  // ---- Wave w stages elem w (f32 -> bf16, [s][q] transposed, swizzled) ----
  {
    const int s = lane;
    const float* xb = x + (bbase + w) * 4096;
    const unsigned sw = ((unsigned)(s & 7)) << 4;
    char* base = XsT + w * 8192 + s * 128;
    #pragma unroll
    for (int c = 0; c < 4; ++c) {               // 16 q per chunk
      unsigned int d[8];
      #pragma unroll
      for (int jj = 0; jj < 8; ++jj) {
        float a  = xb[(c * 16 + 2 * jj + 0) * 64 + s];
        float bq = xb[(c * 16 + 2 * jj + 1) * 64 + s];
        d[jj] = pkcvt(a, bq);
      }
      u32x4 v0 = {d[0], d[1], d[2], d[3]};
      u32x4 v1 = {d[4], d[5], d[6], d[7]};
      *(u32x4*)(base + (((unsigned)(c * 32)) ^ sw))      = v0;
      *(u32x4*)(base + (((unsigned)(c * 32 + 16)) ^ sw)) = v1;
    }
  }
  __syncthreads();   // one-time full drain: X + ring slots 0,1 + b1(0) all landed

  // ---- Hoist GEMM1 A-frags for both elems (loop-invariant): 16 ds_read_b128
  sh8 af[2][2][4];
  #pragma unroll
  for (int e = 0; e < 2; ++e) {
    const char* myX = XsT + (ep + e) * 8192;
    #pragma unroll
    for (int st = 0; st < 2; ++st)
      #pragma unroll
      for (int kq = 0; kq < 4; ++kq) {
        int srow = st * 32 + l31;
        unsigned boff = (unsigned)srow * 128 +
                        (((unsigned)(kq * 32 + h * 16)) ^ (((unsigned)(srow & 7)) << 4));
        af[e][st][kq] = *(const sh8*)(myX + boff);
      }
  }

  const fx16 zc = fzero16();
  fx16 accO[2][2];                 // [elem][nt]
  accO[0][0] = zc; accO[0][1] = zc;
  accO[1][0] = zc; accO[1][1] = zc;

  #pragma unroll 1
  for (int t2 = 0; t2 < 16; ++t2) {
    char* cur = WL + (t2 % 3) * 8192;

    // ---- counted sync: stage(t2) landed on THIS wave (in-order vmcnt),
    //      barrier publishes all waves' slices + fences ring WAR ----
    if (t2 < 15) {
      asm volatile("s_waitcnt vmcnt(16)" ::: "memory");
    } else {
      asm volatile("s_waitcnt vmcnt(8)" ::: "memory");
    }
    __builtin_amdgcn_s_barrier();
    __builtin_amdgcn_sched_barrier(0);

    // ---- issue stage of t2+2 into recycled ring slot (fenced by barrier) ----
    if (t2 < 14) {
      char* dst = WL + ((t2 + 2) % 3) * 8192;
      const size_t toff = (size_t)(t2 + 2) * 8192;
      #pragma unroll
      for (int c = 0; c < 2; ++c) {
        const char* src = w2c + toff + c * 4096 + w * 1024 + lane * 16;
        __builtin_amdgcn_global_load_lds((const unsigned int*)src,
                                         (unsigned int*)(dst + c * 4096 + w * 1024),
                                         16, 0, 0);
      }
    }

    // ---- b2 nt=0 frags from LDS (4 ds_read_b128) ----
    sh8 b2a[4];
    #pragma unroll
    for (int ks = 0; ks < 4; ++ks)
      b2a[ks] = *(const sh8*)(cur + (((0 * 4 + ks) * 64 + lane) << 4));

    // ---- GEMM1 elem0: 8 MFMA, 2 st-chains (b1 already in regs) ----
    fx16 accY[2];
    __builtin_amdgcn_s_setprio(1);
    accY[0] = __builtin_amdgcn_mfma_f32_32x32x16_bf16(af[0][0][0], b1[0], zc, 0, 0, 0);
    accY[1] = __builtin_amdgcn_mfma_f32_32x32x16_bf16(af[0][1][0], b1[0], zc, 0, 0, 0);
    #pragma unroll
    for (int kq = 1; kq < 4; ++kq) {
      accY[0] = __builtin_amdgcn_mfma_f32_32x32x16_bf16(af[0][0][kq], b1[kq], accY[0], 0, 0, 0);
      accY[1] = __builtin_amdgcn_mfma_f32_32x32x16_bf16(af[0][1][kq], b1[kq], accY[1], 0, 0, 0);
    }
    __builtin_amdgcn_s_setprio(0);

    // ---- pack elem0 -> ga0 (16x cvt_pk; sigma in W2) ----
    sh8 ga0[4];
    #pragma unroll
    for (int st = 0; st < 2; ++st) {
      fx16 Y = accY[st];
      union { u32x4 u; sh8 s8; } c0, c1;
      c0.u = (u32x4){pkcvt(Y[0], Y[1]),  pkcvt(Y[2], Y[3]),
                     pkcvt(Y[4], Y[5]),  pkcvt(Y[6], Y[7])};
      c1.u = (u32x4){pkcvt(Y[8], Y[9]),  pkcvt(Y[10], Y[11]),
                     pkcvt(Y[12], Y[13]), pkcvt(Y[14], Y[15])};
      ga0[st * 2 + 0] = c0.s8;
      ga0[st * 2 + 1] = c1.s8;
    }

    // ---- b2 nt=1 frags from LDS (4 ds_read_b128, spread the LDS queue) ----
    sh8 b2b[4];
    #pragma unroll
    for (int ks = 0; ks < 4; ++ks)
      b2b[ks] = *(const sh8*)(cur + (((1 * 4 + ks) * 64 + lane) << 4));

    // ---- GEMM1 elem1: 8 MFMA; last reads of b1 ----
    fx16 accZ[2];
    __builtin_amdgcn_s_setprio(1);
    accZ[0] = __builtin_amdgcn_mfma_f32_32x32x16_bf16(af[1][0][0], b1[0], zc, 0, 0, 0);
    accZ[1] = __builtin_amdgcn_mfma_f32_32x32x16_bf16(af[1][1][0], b1[0], zc, 0, 0, 0);
    #pragma unroll
    for (int kq = 1; kq < 4; ++kq) {
      accZ[0] = __builtin_amdgcn_mfma_f32_32x32x16_bf16(af[1][0][kq], b1[kq], accZ[0], 0, 0, 0);
      accZ[1] = __builtin_amdgcn_mfma_f32_32x32x16_bf16(af[1][1][kq], b1[kq], accZ[1], 0, 0, 0);
    }
    __builtin_amdgcn_s_setprio(0);

    // ---- b1 reload for t2+1 (VMEM into same regs; WAR after GEMM1-e1) ----
    {
      const int t2n = (t2 + 1) & 15;
      #pragma unroll
      for (int kq = 0; kq < 4; ++kq)
        b1[kq] = w1f[t2n * 512 + (mh * 4 + kq) * 64 + lane];
    }

    // ---- GEMM2 elem0 ----
    __builtin_amdgcn_s_setprio(1);
    #pragma unroll
    for (int ks = 0; ks < 4; ++ks) {
      accO[0][0] = __builtin_amdgcn_mfma_f32_32x32x16_bf16(ga0[ks], b2a[ks], accO[0][0], 0, 0, 0);
      accO[0][1] = __builtin_amdgcn_mfma_f32_32x32x16_bf16(ga0[ks], b2b[ks], accO[0][1], 0, 0, 0);
    }
    __builtin_amdgcn_s_setprio(0);

    // ---- pack elem1 -> ga1 ----
    sh8 ga1[4];
    #pragma unroll
    for (int st = 0; st < 2; ++st) {
      fx16 Y = accZ[st];
      union { u32x4 u; sh8 s8; } c0, c1;
      c0.u = (u32x4){pkcvt(Y[0], Y[1]),  pkcvt(Y[2], Y[3]),
                     pkcvt(Y[4], Y[5]),  pkcvt(Y[6], Y[7])};
      c1.u = (u32x4){pkcvt(Y[8], Y[9]),  pkcvt(Y[10], Y[11]),
                     pkcvt(Y[12], Y[13]), pkcvt(Y[14], Y[15])};
      ga1[st * 2 + 0] = c0.s8;
      ga1[st * 2 + 1] = c1.s8;
    }

    // ---- GEMM2 elem1 ----
    __builtin_amdgcn_s_setprio(1);
    #pragma unroll
    for (int ks = 0; ks < 4; ++ks) {
      accO[1][0] = __builtin_amdgcn_mfma_f32_32x32x16_bf16(ga1[ks], b2a[ks], accO[1][0], 0, 0, 0);
      accO[1][1] = __builtin_amdgcn_mfma_f32_32x32x16_bf16(ga1[ks], b2b[ks], accO[1][1], 0, 0, 0);
    }
    __builtin_amdgcn_s_setprio(0);
    // NO end-of-iter drain: stages stay in flight across the next barrier
  }

  // ---- epilogue ----
  #pragma unroll
  for (int e = 0; e < 2; ++e) {
    float* ob = out + (bbase + ep + e) * 4096;
    #pragma unroll
    for (int nt = 0; nt < 2; ++nt) {
      #pragma unroll
      for (int reg = 0; reg < 16; ++reg) {
        int m = mh * 32 + (reg & 3) + 8 * (reg >> 2) + 4 * h;
        int n = nt * 32 + l31;
        int o = m * 64 + n;
        ob[o] = accO[e][nt][reg] + bias[o];
      }
    }
  }
}

// ---------------------------------------------------------------------------
extern "C" void kernel_launch(void* const* d_in, const int* in_sizes, int n_in,
                              void* d_out, int out_size, void* d_ws, size_t ws_size,
                              hipStream_t stream) {
  (void)n_in; (void)out_size; (void)ws_size;
  const float* x    = (const float*)d_in[0];
  const float* P0   = (const float*)d_in[1];
  const float* P1   = (const float*)d_in[2];
  const float* P2   = (const float*)d_in[3];
  const float* P3   = (const float*)d_in[4];
  const float* bias = (const float*)d_in[5];
  float* out = (float*)d_out;

  // ws: Qbuf f32[128*256] (128 KB) | W1 bf16[65536] (128 KB) | W2 bf16[65536] (128 KB)
  float* Qbuf = (float*)d_ws;
  unsigned short* W1 = (unsigned short*)((char*)d_ws + 131072);
  unsigned short* W2 = (unsigned short*)((char*)d_ws + 262144);

  k_cayley<<<8, 256, 0, stream>>>(P1, P2, Qbuf);
  k_build<<<512, 256, 0, stream>>>(P0, P3, Qbuf, W1, W2);

  int batch = in_sizes[0] / 4096;
  k_main<<<batch / 4, 256, 0, stream>>>(x, W1, W2, bias, out);
}

// Round 18
// 137.411 us; speedup vs baseline: 1.0214x; 1.0214x over previous
//
#include <hip/hip_runtime.h>
#include <hip/hip_bf16.h>

typedef __attribute__((ext_vector_type(8))) short sh8;        // 8 x bf16 bits (4 VGPR)
typedef __attribute__((ext_vector_type(16))) float fx16;      // MFMA 32x32 accumulator
typedef __attribute__((ext_vector_type(4))) unsigned int u32x4;

__device__ __forceinline__ unsigned short f2bits(float a) {
  union { __hip_bfloat16 h; unsigned short u; } c;
  c.h = __float2bfloat16(a);
  return c.u;
}
// one-instruction RNE pack: lo = cvt(a), hi = cvt(b)
__device__ __forceinline__ unsigned int pkcvt(float a, float b) {
  unsigned int r;
  asm("v_cvt_pk_bf16_f32 %0, %1, %2" : "=v"(r) : "v"(a), "v"(b));
  return r;
}
__device__ __forceinline__ fx16 fzero16() {
  fx16 z;
  #pragma unroll
  for (int i = 0; i < 16; ++i) z[i] = 0.0f;
  return z;
}

// ---------------------------------------------------------------------------
// Kernel 1: batched Cayley transform Q = (I-A)(I+A)^-1 for P1 (64) and P2 (64).
// ---------------------------------------------------------------------------
__global__ void k_cayley(const float* __restrict__ P1, const float* __restrict__ P2,
                         float* __restrict__ Qout) {
  int t = blockIdx.x * blockDim.x + threadIdx.x;
  int mat = t >> 4;
  int row = t & 15;
  if (mat >= 128) return;
  const float* P = (mat < 64) ? (P1 + mat * 256) : (P2 + (mat - 64) * 256);
  float M[16], Rr[16];
  #pragma unroll
  for (int j = 0; j < 16; ++j) {
    float a = 0.0f;
    if (j > row) a = P[row * 16 + j];
    if (j < row) a = -P[j * 16 + row];
    float d = (j == row) ? 1.0f : 0.0f;
    M[j]  = d + a;
    Rr[j] = d - a;
  }
  int gbase = (threadIdx.x & 63) & ~15;
  #pragma unroll
  for (int k = 0; k < 16; ++k) {
    float pkk = __shfl(M[k], gbase + k);
    float inv = 1.0f / pkk;
    float pM[16], pR[16];
    #pragma unroll
    for (int j = 0; j < 16; ++j) {
      pM[j] = __shfl(M[j], gbase + k) * inv;
      pR[j] = __shfl(Rr[j], gbase + k) * inv;
    }
    if (row == k) {
      #pragma unroll
      for (int j = 0; j < 16; ++j) { M[j] = pM[j]; Rr[j] = pR[j]; }
    } else {
      float f = M[k];
      #pragma unroll
      for (int j = 0; j < 16; ++j) { M[j] -= f * pM[j]; Rr[j] -= f * pR[j]; }
    }
  }
  float* qo = Qout + mat * 256 + row * 16;
  #pragma unroll
  for (int j = 0; j < 16; ++j) qo[j] = Rr[j];
}

// ---------------------------------------------------------------------------
// Kernel 2: build folded weights in bf16, MFMA B-fragment order.
// W1[t2][tile(2)][kstep(4)][lane(64)][r(8)]: k-map q = kstep*16 + 8h + r.
// W2[t2][tile(2)][kstep(4)][lane(64)][r(8)]: k-map s = kstep*16 + sigma(h,r),
//   sigma(h,r) = (r&3) + 8*(r>>2) + 4h  -- so GEMM2's A-frag is accY regs
//   in order after v_cvt_pk (no cross-lane permute).
// ---------------------------------------------------------------------------
__global__ void k_build(const float* __restrict__ P0, const float* __restrict__ P3,
                        const float* __restrict__ Qbuf,
                        unsigned short* __restrict__ W1, unsigned short* __restrict__ W2) {
  int t = blockIdx.x * blockDim.x + threadIdx.x;
  if (t >= 131072) return;
  const float* Q1 = Qbuf;
  const float* Q2 = Qbuf + 16384;
  int e  = t & 65535;
  int r  = e & 7;
  int l  = (e >> 3) & 63;
  int kx = (e >> 9) & 3;
  int mt = (e >> 11) & 1;
  int t2 = (e >> 12) & 15;
  float acc = 0.0f;
  if (t < 65536) {
    int m = mt * 32 + (l & 31);
    int q = kx * 16 + ((l >> 5) << 3) + r;
    int j0 = m >> 3, j1 = m & 7, i0 = q >> 3, i1 = q & 7;
    #pragma unroll
    for (int t1 = 0; t1 < 16; ++t1) {
      float c0 = P0[(j0 * 8 + (t1 >> 1)) * 16 + ((t1 & 1) * 8 + i0)];
      int a1 = j1 * 16 + t2, u1 = t1 * 8 + i1;
      float c1 = Q1[((a1 & 7) * 8 + (u1 >> 4)) * 256 + (a1 >> 3) * 16 + (u1 & 15)];
      acc += c0 * c1;
    }
    W1[e] = f2bits(acc);
  } else {
    int n = mt * 32 + (l & 31);
    int s = kx * 16 + (r & 3) + 8 * (r >> 2) + 4 * (l >> 5);   // sigma-permuted k-map
    int j2 = n >> 3, j3 = n & 7, i2 = s >> 3, i3 = s & 7;
    #pragma unroll
    for (int t3 = 0; t3 < 16; ++t3) {
      int a2 = j2 * 16 + t3, u2 = t2 * 8 + i2;
      float c2 = Q2[((a2 & 7) * 8 + (u2 >> 4)) * 256 + (a2 >> 3) * 16 + (u2 & 15)];
      float c3 = P3[((t3 & 7) * 8 + i3) * 16 + (j3 * 2 + (t3 >> 3))];
      acc += c2 * c3;
    }
    W2[e] = f2bits(acc);
  }
}

// ---------------------------------------------------------------------------
// Kernel 3 (R13 verified structure, 2 t2-slices per barrier window).
// WG = 4 waves / 4 batch elems; wave = (elem-pair, m-half). 8 windows; each
// stages the NEXT window's 2 W2 slices (16 KB) into the dbuf half, runs
// R13's verified per-t2 body twice (b1 via VMEM same-reg prefetch, b2 via
// LDS, sigma-pack, split GEMM2s), then ONE vmcnt(0)+__syncthreads. Halves
// the number of drain+barrier events vs R13. LDS 64 KB -> 2 WGs/CU.
// ---------------------------------------------------------------------------
__global__ __launch_bounds__(256, 2) void k_main(
    const float* __restrict__ x,
    const unsigned short* __restrict__ W1,
    const unsigned short* __restrict__ W2,
    const float* __restrict__ bias,
    float* __restrict__ out) {
  __shared__ __align__(16) char smem[4 * 8192 + 2 * 16384];
  char* XsT = smem;                 // [elem][64 s][128 B], swizzled
  char* WL  = smem + 32768;         // [2][16384]: dbuf, each = 2 W2 slices

  const int tid  = threadIdx.x;
  const int lane = tid & 63;
  const int w    = tid >> 6;
  const int h    = lane >> 5;
  const int l31  = lane & 31;
  const int ep   = (w >> 1) * 2;    // first elem of this wave's pair
  const int mh   = w & 1;           // m-half this wave owns
  const size_t bbase = (size_t)blockIdx.x * 4;

  const char* w2c = (const char*)W2;
  const sh8* w1f = (const sh8*)W1;   // idx: t2*512 + (tile*4+kstep)*64 + lane

  // ---- stage W2 slices 0,1 into dbuf half 0 (4 chunks x 256 thr x 16B) ----
  #pragma unroll
  for (int c = 0; c < 4; ++c) {
    const char* src = w2c + c * 4096 + w * 1024 + lane * 16;
    __builtin_amdgcn_global_load_lds((const unsigned int*)src,
                                     (unsigned int*)(WL + c * 4096 + w * 1024),
                                     16, 0, 0);
  }

  // ---- b1(0) into regs (VMEM; latency covered by X staging) ----
  sh8 b1[4];
  #pragma unroll
  for (int kq = 0; kq < 4; ++kq)
    b1[kq] = w1f[(mh * 4 + kq) * 64 + lane];

  // ---- Wave w stages elem w (f32 -> bf16, [s][q] transposed, swizzled) ----
  {
    const int s = lane;
    const float* xb = x + (bbase + w) * 4096;
    const unsigned sw = ((unsigned)(s & 7)) << 4;
    char* base = XsT + w * 8192 + s * 128;
    #pragma unroll
    for (int c = 0; c < 4; ++c) {               // 16 q per chunk
      unsigned int d[8];
      #pragma unroll
      for (int jj = 0; jj < 8; ++jj) {
        float a  = xb[(c * 16 + 2 * jj + 0) * 64 + s];
        float bq = xb[(c * 16 + 2 * jj + 1) * 64 + s];
        d[jj] = pkcvt(a, bq);
      }
      u32x4 v0 = {d[0], d[1], d[2], d[3]};
      u32x4 v1 = {d[4], d[5], d[6], d[7]};
      *(u32x4*)(base + (((unsigned)(c * 32)) ^ sw))      = v0;
      *(u32x4*)(base + (((unsigned)(c * 32 + 16)) ^ sw)) = v1;
    }
  }
  asm volatile("s_waitcnt vmcnt(0)" ::: "memory");
  __syncthreads();

  // ---- Hoist GEMM1 A-frags for both elems (loop-invariant): 16 ds_read_b128
  sh8 af[2][2][4];
  #pragma unroll
  for (int e = 0; e < 2; ++e) {
    const char* myX = XsT + (ep + e) * 8192;
    #pragma unroll
    for (int st = 0; st < 2; ++st)
      #pragma unroll
      for (int kq = 0; kq < 4; ++kq) {
        int srow = st * 32 + l31;
        unsigned boff = (unsigned)srow * 128 +
                        (((unsigned)(kq * 32 + h * 16)) ^ (((unsigned)(srow & 7)) << 4));
        af[e][st][kq] = *(const sh8*)(myX + boff);
      }
  }

  const fx16 zc = fzero16();
  fx16 accO[2][2];                 // [elem][nt]
  accO[0][0] = zc; accO[0][1] = zc;
  accO[1][0] = zc; accO[1][1] = zc;

  #pragma unroll 1
  for (int win = 0; win < 8; ++win) {
    char* curw = WL + (win & 1) * 16384;

    // ---- stage NEXT window's 2 slices into the other half (8 chunks) ----
    if (win < 7) {
      char* dst = WL + ((win + 1) & 1) * 16384;
      const size_t toff = (size_t)(win + 1) * 16384;
      #pragma unroll
      for (int c = 0; c < 4; ++c) {
        const char* src = w2c + toff + c * 4096 + w * 1024 + lane * 16;
        __builtin_amdgcn_global_load_lds((const unsigned int*)src,
                                         (unsigned int*)(dst + c * 4096 + w * 1024),
                                         16, 0, 0);
      }
    }

    // ================== two verified R13 bodies per window ==================
    #pragma unroll
    for (int tt = 0; tt < 2; ++tt) {
      const int t2 = win * 2 + tt;
      const char* cur = curw + tt * 8192;

      // ---- b2 nt=0 frags from LDS (4 ds_read_b128) ----
      sh8 b2a[4];
      #pragma unroll
      for (int ks = 0; ks < 4; ++ks)
        b2a[ks] = *(const sh8*)(cur + (((0 * 4 + ks) * 64 + lane) << 4));

      // ---- GEMM1 elem0: 8 MFMA, 2 st-chains ----
      fx16 accY[2];
      __builtin_amdgcn_s_setprio(1);
      accY[0] = __builtin_amdgcn_mfma_f32_32x32x16_bf16(af[0][0][0], b1[0], zc, 0, 0, 0);
      accY[1] = __builtin_amdgcn_mfma_f32_32x32x16_bf16(af[0][1][0], b1[0], zc, 0, 0, 0);
      #pragma unroll
      for (int kq = 1; kq < 4; ++kq) {
        accY[0] = __builtin_amdgcn_mfma_f32_32x32x16_bf16(af[0][0][kq], b1[kq], accY[0], 0, 0, 0);
        accY[1] = __builtin_amdgcn_mfma_f32_32x32x16_bf16(af[0][1][kq], b1[kq], accY[1], 0, 0, 0);
      }
      __builtin_amdgcn_s_setprio(0);

      // ---- pack elem0 -> ga0 ----
      sh8 ga0[4];
      #pragma unroll
      for (int st = 0; st < 2; ++st) {
        fx16 Y = accY[st];
        union { u32x4 u; sh8 s8; } c0, c1;
        c0.u = (u32x4){pkcvt(Y[0], Y[1]),  pkcvt(Y[2], Y[3]),
                       pkcvt(Y[4], Y[5]),  pkcvt(Y[6], Y[7])};
        c1.u = (u32x4){pkcvt(Y[8], Y[9]),  pkcvt(Y[10], Y[11]),
                       pkcvt(Y[12], Y[13]), pkcvt(Y[14], Y[15])};
        ga0[st * 2 + 0] = c0.s8;
        ga0[st * 2 + 1] = c1.s8;
      }

      // ---- b2 nt=1 frags ----
      sh8 b2b[4];
      #pragma unroll
      for (int ks = 0; ks < 4; ++ks)
        b2b[ks] = *(const sh8*)(cur + (((1 * 4 + ks) * 64 + lane) << 4));

      // ---- GEMM1 elem1: 8 MFMA; last reads of b1 ----
      fx16 accZ[2];
      __builtin_amdgcn_s_setprio(1);
      accZ[0] = __builtin_amdgcn_mfma_f32_32x32x16_bf16(af[1][0][0], b1[0], zc, 0, 0, 0);
      accZ[1] = __builtin_amdgcn_mfma_f32_32x32x16_bf16(af[1][1][0], b1[0], zc, 0, 0, 0);
      #pragma unroll
      for (int kq = 1; kq < 4; ++kq) {
        accZ[0] = __builtin_amdgcn_mfma_f32_32x32x16_bf16(af[1][0][kq], b1[kq], accZ[0], 0, 0, 0);
        accZ[1] = __builtin_amdgcn_mfma_f32_32x32x16_bf16(af[1][1][kq], b1[kq], accZ[1], 0, 0, 0);
      }
      __builtin_amdgcn_s_setprio(0);

      // ---- b1 reload for t2+1 (VMEM, same regs; WAR after GEMM1-e1) ----
      {
        const int t2n = (t2 + 1) & 15;
        #pragma unroll
        for (int kq = 0; kq < 4; ++kq)
          b1[kq] = w1f[t2n * 512 + (mh * 4 + kq) * 64 + lane];
      }

      // ---- GEMM2 elem0 ----
      __builtin_amdgcn_s_setprio(1);
      #pragma unroll
      for (int ks = 0; ks < 4; ++ks) {
        accO[0][0] = __builtin_amdgcn_mfma_f32_32x32x16_bf16(ga0[ks], b2a[ks], accO[0][0], 0, 0, 0);
        accO[0][1] = __builtin_amdgcn_mfma_f32_32x32x16_bf16(ga0[ks], b2b[ks], accO[0][1], 0, 0, 0);
      }
      __builtin_amdgcn_s_setprio(0);

      // ---- pack elem1 -> ga1 ----
      sh8 ga1[4];
      #pragma unroll
      for (int st = 0; st < 2; ++st) {
        fx16 Y = accZ[st];
        union { u32x4 u; sh8 s8; } c0, c1;
        c0.u = (u32x4){pkcvt(Y[0], Y[1]),  pkcvt(Y[2], Y[3]),
                       pkcvt(Y[4], Y[5]),  pkcvt(Y[6], Y[7])};
        c1.u = (u32x4){pkcvt(Y[8], Y[9]),  pkcvt(Y[10], Y[11]),
                       pkcvt(Y[12], Y[13]), pkcvt(Y[14], Y[15])};
        ga1[st * 2 + 0] = c0.s8;
        ga1[st * 2 + 1] = c1.s8;
      }

      // ---- GEMM2 elem1 ----
      __builtin_amdgcn_s_setprio(1);
      #pragma unroll
      for (int ks = 0; ks < 4; ++ks) {
        accO[1][0] = __builtin_amdgcn_mfma_f32_32x32x16_bf16(ga1[ks], b2a[ks], accO[1][0], 0, 0, 0);
        accO[1][1] = __builtin_amdgcn_mfma_f32_32x32x16_bf16(ga1[ks], b2b[ks], accO[1][1], 0, 0, 0);
      }
      __builtin_amdgcn_s_setprio(0);
    }

    // ---- ONE drain+barrier per 2 slices ----
    asm volatile("s_waitcnt vmcnt(0)" ::: "memory");
    __syncthreads();
  }

  // ---- epilogue ----
  #pragma unroll
  for (int e = 0; e < 2; ++e) {
    float* ob = out + (bbase + ep + e) * 4096;
    #pragma unroll
    for (int nt = 0; nt < 2; ++nt) {
      #pragma unroll
      for (int reg = 0; reg < 16; ++reg) {
        int m = mh * 32 + (reg & 3) + 8 * (reg >> 2) + 4 * h;
        int n = nt * 32 + l31;
        int o = m * 64 + n;
        ob[o] = accO[e][nt][reg] + bias[o];
      }
    }
  }
}

// ---------------------------------------------------------------------------
extern "C" void kernel_launch(void* const* d_in, const int* in_sizes, int n_in,
                              void* d_out, int out_size, void* d_ws, size_t ws_size,
                              hipStream_t stream) {
  (void)n_in; (void)out_size; (void)ws_size;
  const float* x    = (const float*)d_in[0];
  const float* P0   = (const float*)d_in[1];
  const float* P1   = (const float*)d_in[2];
  const float* P2   = (const float*)d_in[3];
  const float* P3   = (const float*)d_in[4];
  const float* bias = (const float*)d_in[5];
  float* out = (float*)d_out;

  // ws: Qbuf f32[128*256] (128 KB) | W1 bf16[65536] (128 KB) | W2 bf16[65536] (128 KB)
  float* Qbuf = (float*)d_ws;
  unsigned short* W1 = (unsigned short*)((char*)d_ws + 131072);
  unsigned short* W2 = (unsigned short*)((char*)d_ws + 262144);

  k_cayley<<<8, 256, 0, stream>>>(P1, P2, Qbuf);
  k_build<<<512, 256, 0, stream>>>(P0, P3, Qbuf, W1, W2);

  int batch = in_sizes[0] / 4096;
  k_main<<<batch / 4, 256, 0, stream>>>(x, W1, W2, bias, out);
}